// Round 7
// baseline (57.648 us; speedup 1.0000x reference)
//
#include <hip/hip_runtime.h>
#include <math.h>

#define C_CLS   19
#define H_IN    97
#define W_IN    97
#define HW_IN   (H_IN * W_IN)
#define CHW_IN  (C_CLS * HW_IN)
#define H_OUT   769
#define W_OUT   769
#define N_BATCH 4
#define IGNORE_LBL 255
#define MIN_KEPT   100000
#define NHI     110          // histogram bins for p in (0.7, 1.0]
#define ACC_STRIDE 1024      // floats per pred histogram block in ws
#define NSETS   256          // striped accumulator sets (1 cache line each)
#define SET_BASE 2048        // ws float offset of striped sets
#define NLL_THR 0.35667494f  // -ln(0.7); p <= 0.7  <=>  nll >= NLL_THR
#define COLS    28           // staged source columns per quarter (need <=27)
#define BLKT    192          // threads per block (3 waves)

// Cityscapes class weights
__device__ const float c_class_w[C_CLS] = {
    0.8373f, 0.918f,  0.866f,  1.0345f, 1.0166f, 0.9969f, 0.9754f,
    1.0489f, 0.8786f, 1.0023f, 0.9539f, 0.9843f, 1.1116f, 0.9037f,
    1.0865f, 1.0955f, 1.0865f, 1.1529f, 1.0507f};

// ws layout (floats):
// [4..333]            hist pred1: cnt / sum_w / sum_wnll  (stride 110 each)
// [1028..1357]        hist pred2
// [2048 + s*16 + k]   striped set s (k: 0=nv 1=w1 2=wlp1 3=cle1 4=w2 5=wlp2 6=cle2)

__global__ __launch_bounds__(BLKT, 8) void ohem_qrow(
    const float* __restrict__ pred1, const float* __restrict__ pred2,
    const int* __restrict__ target, float* __restrict__ ws)
{
    const int bid = blockIdx.x;           // row-quarter id
    const int row = bid >> 2;             // 0 .. 3075
    const int q   = bid & 3;
    const int n   = row / H_OUT;
    const int y   = row - n * H_OUT;
    const int tid = threadIdx.x;

    const int qlo  = q ? q * 192 + 1 : 0;         // 0 | 193 | 385 | 577
    const int qlen = q ? 192 : 193;

    __shared__ float ry[2][C_CLS][COLS];  // y-interpolated source cols (quarter)
    __shared__ float wtab[C_CLS];
    __shared__ float sh_red[3][8];

    if (tid < C_CLS) wtab[tid] = c_class_w[tid];

    const float scl = (float)H_IN / (float)H_OUT;

    // ---- y-interp params (uniform over row) ----
    float sy = fmaxf(fmaf((float)y + 0.5f, scl, -0.5f), 0.0f);
    int   y0 = min((int)sy, H_IN - 1);
    float fy = sy - (float)y0;
    int   y1 = min(y0 + 1, H_IN - 1);

    // ---- first staged source column of this quarter ----
    int c_lo = max((int)floorf(fmaf((float)qlo + 0.5f, scl, -0.5f)), 0);

    // ---- prefetch this thread's target(s) early (latency overlaps staging) ----
    const int rowbase = (n * H_OUT + y) * W_OUT;
    int x_px = qlo + tid;                  // always < 769 (qlen >= 192)
    int t_px = target[rowbase + x_px];
    int t_ex = 0;
    if (q == 0 && tid == 0) t_ex = target[rowbase + 192];   // q0's 193rd pixel

    // ---- stage y-interpolated quarter rows into LDS ----
    const float* __restrict__ b1 = pred1 + (size_t)n * CHW_IN;
    const float* __restrict__ b2 = pred2 + (size_t)n * CHW_IN;
    for (int i = tid; i < C_CLS * COLS; i += BLKT) {
        int c = i / COLS;
        int j = i - c * COLS;
        int gcol = min(c_lo + j, W_IN - 1);        // clamp pads right edge
        int o0 = c * HW_IN + y0 * W_IN + gcol;
        int o1 = c * HW_IN + y1 * W_IN + gcol;
        float a0 = b1[o0], a1 = b1[o1];
        float c0 = b2[o0], c1 = b2[o1];
        ry[0][c][j] = fmaf(fy, a1 - a0, a0);
        ry[1][c][j] = fmaf(fy, c1 - c0, c0);
    }
    __syncthreads();

    float a_nv = 0.f;
    float a_w1 = 0.f, a_wlp1 = 0.f, a_cle1 = 0.f;
    float a_w2 = 0.f, a_wlp2 = 0.f, a_cle2 = 0.f;

    // ---- per-pixel work: 1 px/thread (+1 extra lane-0 px in q0) ----
    #pragma unroll 1
    for (int k = tid; k < qlen; k += BLKT) {
        int x = qlo + k;
        int t = (k == tid) ? t_px : t_ex;

        float sx = fmaxf(fmaf((float)x + 0.5f, scl, -0.5f), 0.0f);
        int   x0 = min((int)sx, W_IN - 1);
        float fx = sx - (float)x0;
        int   ix = x0 - c_lo;

        float s1a = 0.f, s1b = 0.f, s2a = 0.f, s2b = 0.f;
        #pragma unroll
        for (int c = 0; c < C_CLS; ++c) {
            float lo1 = ry[0][c][ix], hi1 = ry[0][c][ix + 1];
            float lo2 = ry[1][c][ix], hi2 = ry[1][c][ix + 1];
            float e1 = __expf(fmaf(fx, hi1 - lo1, lo1));
            float e2 = __expf(fmaf(fx, hi2 - lo2, lo2));
            if (c & 1) { s1b += e1; s2b += e2; }
            else       { s1a += e1; s2a += e2; }
        }
        float s1 = s1a + s1b;
        float s2 = s2a + s2b;

        if (t != IGNORE_LBL) {
            int ts = t;
            float u0 = ry[0][ts][ix], u1 = ry[0][ts][ix + 1];
            float v0 = ry[1][ts][ix], v1 = ry[1][ts][ix + 1];
            float lt1 = fmaf(fx, u1 - u0, u0);
            float lt2 = fmaf(fx, v1 - v0, v0);
            float w   = wtab[ts];
            float nll1 = __logf(s1) - lt1;
            float nll2 = __logf(s2) - lt2;
            a_nv += 1.0f;

            if (nll1 >= NLL_THR) {            // p1 <= 0.7 (common)
                a_w1 += w; a_wlp1 = fmaf(w, nll1, a_wlp1); a_cle1 += 1.f;
            } else {                          // rare: direct global hist
                float p = __expf(-nll1);
                int b = min(max((int)((p - 0.7f) * (109.f / 0.3f)), 0), NHI - 1);
                atomicAdd(&ws[4 + b],   1.f);
                atomicAdd(&ws[114 + b], w);
                atomicAdd(&ws[224 + b], w * nll1);
            }
            if (nll2 >= NLL_THR) {            // p2 <= 0.7 (common)
                a_w2 += w; a_wlp2 = fmaf(w, nll2, a_wlp2); a_cle2 += 1.f;
            } else {
                float p = __expf(-nll2);
                int b = min(max((int)((p - 0.7f) * (109.f / 0.3f)), 0), NHI - 1);
                atomicAdd(&ws[ACC_STRIDE + 4 + b],   1.f);
                atomicAdd(&ws[ACC_STRIDE + 114 + b], w);
                atomicAdd(&ws[ACC_STRIDE + 224 + b], w * nll2);
            }
        }
    }

    // ---- wave butterfly reduce, 7 values ----
    #pragma unroll
    for (int off = 32; off > 0; off >>= 1) {
        a_nv   += __shfl_down(a_nv, off);
        a_w1   += __shfl_down(a_w1, off);
        a_wlp1 += __shfl_down(a_wlp1, off);
        a_cle1 += __shfl_down(a_cle1, off);
        a_w2   += __shfl_down(a_w2, off);
        a_wlp2 += __shfl_down(a_wlp2, off);
        a_cle2 += __shfl_down(a_cle2, off);
    }
    int lane = tid & 63;
    int wv   = tid >> 6;                   // 0..2
    if (lane == 0) {
        sh_red[wv][0] = a_nv;
        sh_red[wv][1] = a_w1; sh_red[wv][2] = a_wlp1; sh_red[wv][3] = a_cle1;
        sh_red[wv][4] = a_w2; sh_red[wv][5] = a_wlp2; sh_red[wv][6] = a_cle2;
    }
    __syncthreads();
    if (tid == 0) {
        float r[7] = {0, 0, 0, 0, 0, 0, 0};
        #pragma unroll
        for (int i = 0; i < 3; ++i)
            #pragma unroll
            for (int j = 0; j < 7; ++j) r[j] += sh_red[i][j];
        float* acc = ws + SET_BASE + (bid & (NSETS - 1)) * 16;
        #pragma unroll
        for (int j = 0; j < 7; ++j) atomicAdd(&acc[j], r[j]);
    }
}

__global__ void ohem_finalize(const float* __restrict__ ws, float* __restrict__ out)
{
    // 64 threads: each folds 4 striped sets, butterfly, lane 0 does OHEM logic
    int lane = threadIdx.x;   // 0..63
    float v[7];
    #pragma unroll
    for (int k = 0; k < 7; ++k) v[k] = 0.f;
    #pragma unroll
    for (int g = 0; g < NSETS / 64; ++g) {
        const float* s = ws + SET_BASE + (lane + g * 64) * 16;
        #pragma unroll
        for (int k = 0; k < 7; ++k) v[k] += s[k];
    }
    #pragma unroll
    for (int off = 32; off > 0; off >>= 1) {
        #pragma unroll
        for (int k = 0; k < 7; ++k) v[k] += __shfl_down(v[k], off);
    }
    if (lane != 0) return;

    float nv = v[0];
    float loss[2];
    for (int pr = 0; pr < 2; ++pr) {
        const float* a = ws + pr * ACC_STRIDE;
        float sw   = pr ? v[4] : v[1];
        float swlp = pr ? v[5] : v[2];
        float cle  = pr ? v[6] : v[3];
        float l;
        if (nv <= (float)MIN_KEPT) {
            float tw = sw, twlp = swlp;
            for (int b = 0; b < NHI; ++b) { tw += a[114 + b]; twlp += a[224 + b]; }
            l = twlp / tw;
        } else if (cle >= (float)MIN_KEPT) {
            l = swlp / sw;
        } else {
            float cum = cle, tw = sw, twlp = swlp;
            for (int b = 0; b < NHI; ++b) {
                cum  += a[4 + b];
                tw   += a[114 + b];
                twlp += a[224 + b];
                if (cum >= (float)MIN_KEPT) break;
            }
            l = twlp / tw;
        }
        loss[pr] = l;
    }
    out[0] = 0.4f * loss[0] + loss[1];
}

extern "C" void kernel_launch(void* const* d_in, const int* in_sizes, int n_in,
                              void* d_out, int out_size, void* d_ws, size_t ws_size,
                              hipStream_t stream)
{
    const float* pred1  = (const float*)d_in[0];
    const float* pred2  = (const float*)d_in[1];
    const int*   target = (const int*)d_in[2];
    float* out = (float*)d_out;
    float* ws  = (float*)d_ws;

    // zero hists (ws[0..2047]) + striped sets (ws[2048..6143])
    hipMemsetAsync(d_ws, 0, (SET_BASE + NSETS * 16) * sizeof(float), stream);

    ohem_qrow<<<dim3(N_BATCH * H_OUT * 4), BLKT, 0, stream>>>(pred1, pred2, target, ws);
    ohem_finalize<<<1, 64, 0, stream>>>(ws, out);
}

// Round 8
// 42.109 us; speedup vs baseline: 1.3690x; 1.3690x over previous
//
#include <hip/hip_runtime.h>
#include <math.h>

#define C_CLS   19
#define H_IN    97
#define W_IN    97
#define HW_IN   (H_IN * W_IN)
#define CHW_IN  (C_CLS * HW_IN)
#define H_OUT   769
#define W_OUT   769
#define N_BATCH 4
#define IGNORE_LBL 255
#define MIN_KEPT   100000
#define NHI     110          // histogram bins for p in (0.7, 1.0]
#define ACC_STRIDE 1024      // floats per pred histogram block in ws
#define NSETS   64           // striped accumulator sets (R4-proven)
#define SET_BASE 2048        // ws float offset of striped sets
#define NLL_THR 0.35667494f  // -ln(0.7); p <= 0.7  <=>  nll >= NLL_THR
#define ROWP    100          // padded LDS row length (>= 98)
#define BLKT    128

// Cityscapes class weights
__device__ const float c_class_w[C_CLS] = {
    0.8373f, 0.918f,  0.866f,  1.0345f, 1.0166f, 0.9969f, 0.9754f,
    1.0489f, 0.8786f, 1.0023f, 0.9539f, 0.9843f, 1.1116f, 0.9037f,
    1.0865f, 1.0955f, 1.0865f, 1.1529f, 1.0507f};

// ws layout (floats):
// [4..333]            hist pred1: cnt / sum_w / sum_wnll  (stride 110 each)
// [1028..1357]        hist pred2
// [2048 + s*16 + k]   striped set s (k: 0=nv 1=w1 2=wlp1 3=cle1 4=w2 5=wlp2 6=cle2)

__global__ __launch_bounds__(BLKT) void ohem_row(
    const float* __restrict__ pred1, const float* __restrict__ pred2,
    const int* __restrict__ target, float* __restrict__ ws)
{
    const int row = blockIdx.x;           // 0 .. 4*769-1
    const int n   = row / H_OUT;
    const int y   = row - n * H_OUT;
    const int tid = threadIdx.x;

    __shared__ float ry[2][C_CLS][ROWP];  // y-interpolated source rows
    __shared__ float wtab[C_CLS];
    __shared__ float sh_red[2][8];

    if (tid < C_CLS) wtab[tid] = c_class_w[tid];

    const float scl = (float)H_IN / (float)H_OUT;   // uniform fx step h

    // ---- column-run assignment (before staging, so target prefetch early) ----
    // thread t<97: source column t, pixels [xs, xe) with unclamped fx, step=scl
    // thread 97:   pixels 0..3 (clamped region, fx = 0), column 0, step = 0
    int col, xs, npx;
    float fx0, hstep;
    if (tid < 97) {
        col = tid;
        xs  = ((2 * tid + 1) * 769 + 96) / 194;
        int xe = min(((2 * tid + 3) * 769 + 96) / 194, 769);
        npx = xe - xs;                    // 7 or 8
        fx0 = fmaf((float)xs + 0.5f, scl, -0.5f) - (float)col;
        hstep = scl;
    } else if (tid == 97) {
        col = 0; xs = 0; npx = 4; fx0 = 0.0f; hstep = 0.0f;   // g==1 path
    } else {
        col = 0; xs = 0; npx = 0; fx0 = 0.0f; hstep = 0.0f;
    }

    // ---- prefetch this thread's targets (latency hides under staging) ----
    const int rowbase = (n * H_OUT + y) * W_OUT;
    int tg[8];
    #pragma unroll
    for (int k = 0; k < 8; ++k)
        tg[k] = target[rowbase + min(xs + k, W_OUT - 1)];

    // ---- y-interp params (uniform over row) ----
    float sy = fmaxf(fmaf((float)y + 0.5f, scl, -0.5f), 0.0f);
    int   y0 = min((int)sy, H_IN - 1);
    float fy = sy - (float)y0;
    int   y1 = min(y0 + 1, H_IN - 1);

    // ---- stage y-interpolated rows into LDS (coalesced) ----
    const float* __restrict__ b1 = pred1 + (size_t)n * CHW_IN;
    const float* __restrict__ b2 = pred2 + (size_t)n * CHW_IN;
    for (int j = tid; j < C_CLS * W_IN; j += BLKT) {
        int c = j / W_IN;
        int x = j - c * W_IN;
        int o0 = c * HW_IN + y0 * W_IN + x;
        int o1 = c * HW_IN + y1 * W_IN + x;
        float a0 = b1[o0], a1 = b1[o1];
        float c0 = b2[o0], c1 = b2[o1];
        float r1 = fmaf(fy, a1 - a0, a0);
        float r2 = fmaf(fy, c1 - c0, c0);
        ry[0][c][x] = r1;
        ry[1][c][x] = r2;
        if (x == W_IN - 1) {              // pad so col+1 read is safe & exact
            ry[0][c][W_IN] = r1;
            ry[1][c][W_IN] = r2;
        }
    }
    __syncthreads();

    // ---- softmax denominators for the 8-px run: incremental exponentials.
    //      exp(a + (fx0+k*h)*d) = e * g^k ; 2 exps + 8 mul/add per chan-pred ----
    float s1[8], s2[8];
    #pragma unroll
    for (int k = 0; k < 8; ++k) { s1[k] = 0.f; s2[k] = 0.f; }

    #pragma unroll
    for (int c = 0; c < C_CLS; ++c) {
        float a1v = ry[0][c][col], b1v = ry[0][c][col + 1];
        float a2v = ry[1][c][col], b2v = ry[1][c][col + 1];
        float d1 = b1v - a1v;
        float d2 = b2v - a2v;
        float e1 = __expf(fmaf(fx0, d1, a1v));
        float e2 = __expf(fmaf(fx0, d2, a2v));
        float g1 = __expf(hstep * d1);
        float g2 = __expf(hstep * d2);
        #pragma unroll
        for (int k = 0; k < 8; ++k) {
            s1[k] += e1; e1 *= g1;
            s2[k] += e2; e2 *= g2;
        }
    }

    // ---- per-pixel epilogue ----
    float a_nv = 0.f;
    float a_w1 = 0.f, a_wlp1 = 0.f, a_cle1 = 0.f;
    float a_w2 = 0.f, a_wlp2 = 0.f, a_cle2 = 0.f;

    #pragma unroll
    for (int k = 0; k < 8; ++k) {
        if (k < npx) {
            int t = tg[k];
            if (t != IGNORE_LBL) {
                int ts = t;
                float fxk = fmaf((float)k, hstep, fx0);
                float u0 = ry[0][ts][col], u1 = ry[0][ts][col + 1];
                float v0 = ry[1][ts][col], v1 = ry[1][ts][col + 1];
                float lt1 = fmaf(fxk, u1 - u0, u0);
                float lt2 = fmaf(fxk, v1 - v0, v0);
                float w   = wtab[ts];
                float nll1 = __logf(s1[k]) - lt1;
                float nll2 = __logf(s2[k]) - lt2;
                a_nv += 1.0f;

                if (nll1 >= NLL_THR) {            // p1 <= 0.7 (common)
                    a_w1 += w; a_wlp1 = fmaf(w, nll1, a_wlp1); a_cle1 += 1.f;
                } else {                          // rare: direct global hist
                    float p = __expf(-nll1);
                    int b = min(max((int)((p - 0.7f) * (109.f / 0.3f)), 0), NHI - 1);
                    atomicAdd(&ws[4 + b],   1.f);
                    atomicAdd(&ws[114 + b], w);
                    atomicAdd(&ws[224 + b], w * nll1);
                }
                if (nll2 >= NLL_THR) {            // p2 <= 0.7 (common)
                    a_w2 += w; a_wlp2 = fmaf(w, nll2, a_wlp2); a_cle2 += 1.f;
                } else {
                    float p = __expf(-nll2);
                    int b = min(max((int)((p - 0.7f) * (109.f / 0.3f)), 0), NHI - 1);
                    atomicAdd(&ws[ACC_STRIDE + 4 + b],   1.f);
                    atomicAdd(&ws[ACC_STRIDE + 114 + b], w);
                    atomicAdd(&ws[ACC_STRIDE + 224 + b], w * nll2);
                }
            }
        }
    }

    // ---- wave butterfly reduce, 7 values ----
    #pragma unroll
    for (int off = 32; off > 0; off >>= 1) {
        a_nv   += __shfl_down(a_nv, off);
        a_w1   += __shfl_down(a_w1, off);
        a_wlp1 += __shfl_down(a_wlp1, off);
        a_cle1 += __shfl_down(a_cle1, off);
        a_w2   += __shfl_down(a_w2, off);
        a_wlp2 += __shfl_down(a_wlp2, off);
        a_cle2 += __shfl_down(a_cle2, off);
    }
    int lane = tid & 63;
    int wv   = tid >> 6;                   // 0..1
    if (lane == 0) {
        sh_red[wv][0] = a_nv;
        sh_red[wv][1] = a_w1; sh_red[wv][2] = a_wlp1; sh_red[wv][3] = a_cle1;
        sh_red[wv][4] = a_w2; sh_red[wv][5] = a_wlp2; sh_red[wv][6] = a_cle2;
    }
    __syncthreads();
    if (tid == 0) {
        float r[7] = {0, 0, 0, 0, 0, 0, 0};
        #pragma unroll
        for (int i = 0; i < 2; ++i)
            #pragma unroll
            for (int j = 0; j < 7; ++j) r[j] += sh_red[i][j];
        float* acc = ws + SET_BASE + (blockIdx.x & (NSETS - 1)) * 16;
        #pragma unroll
        for (int j = 0; j < 7; ++j) atomicAdd(&acc[j], r[j]);
    }
}

__global__ void ohem_finalize(const float* __restrict__ ws, float* __restrict__ out)
{
    // single 64-thread block: reduce 64 striped sets, then OHEM logic on lane 0
    int lane = threadIdx.x;   // 0..63
    float v[7];
    #pragma unroll
    for (int k = 0; k < 7; ++k) v[k] = ws[SET_BASE + lane * 16 + k];
    #pragma unroll
    for (int off = 32; off > 0; off >>= 1) {
        #pragma unroll
        for (int k = 0; k < 7; ++k) v[k] += __shfl_down(v[k], off);
    }
    if (lane != 0) return;

    float nv = v[0];
    float loss[2];
    for (int pr = 0; pr < 2; ++pr) {
        const float* a = ws + pr * ACC_STRIDE;
        float sw   = pr ? v[4] : v[1];
        float swlp = pr ? v[5] : v[2];
        float cle  = pr ? v[6] : v[3];
        float l;
        if (nv <= (float)MIN_KEPT) {
            float tw = sw, twlp = swlp;
            for (int b = 0; b < NHI; ++b) { tw += a[114 + b]; twlp += a[224 + b]; }
            l = twlp / tw;
        } else if (cle >= (float)MIN_KEPT) {
            l = swlp / sw;
        } else {
            float cum = cle, tw = sw, twlp = swlp;
            for (int b = 0; b < NHI; ++b) {
                cum  += a[4 + b];
                tw   += a[114 + b];
                twlp += a[224 + b];
                if (cum >= (float)MIN_KEPT) break;
            }
            l = twlp / tw;
        }
        loss[pr] = l;
    }
    out[0] = 0.4f * loss[0] + loss[1];
}

extern "C" void kernel_launch(void* const* d_in, const int* in_sizes, int n_in,
                              void* d_out, int out_size, void* d_ws, size_t ws_size,
                              hipStream_t stream)
{
    const float* pred1  = (const float*)d_in[0];
    const float* pred2  = (const float*)d_in[1];
    const int*   target = (const int*)d_in[2];
    float* out = (float*)d_out;
    float* ws  = (float*)d_ws;

    // zero hists (ws[0..2047]) + striped sets
    hipMemsetAsync(d_ws, 0, (SET_BASE + NSETS * 16) * sizeof(float), stream);

    ohem_row<<<dim3(N_BATCH * H_OUT), BLKT, 0, stream>>>(pred1, pred2, target, ws);
    ohem_finalize<<<1, 64, 0, stream>>>(ws, out);
}

// Round 9
// 39.624 us; speedup vs baseline: 1.4549x; 1.0627x over previous
//
#include <hip/hip_runtime.h>
#include <math.h>

#define C_CLS   19
#define H_IN    97
#define W_IN    97
#define HW_IN   (H_IN * W_IN)
#define CHW_IN  (C_CLS * HW_IN)
#define H_OUT   769
#define W_OUT   769
#define N_BATCH 4
#define NROWS   (N_BATCH * H_OUT)    // 3076
#define GRIDB   1538                 // blocks; each does rows {bid, bid+1538}
#define IGNORE_LBL 255
#define MIN_KEPT   100000
#define NHI     110
#define ACC_STRIDE 1024
#define NSETS   64
#define SET_BASE 2048
#define NLL_THR 0.35667494f          // -ln(0.7)
#define ROWP    98                   // 97 cols + dup pad
#define NELEM   (2 * C_CLS * ROWP)   // 3724 floats staged per row
#define PCR     (C_CLS * ROWP)       // 1862
#define NSLOT   15                   // ceil(3724/256)
#define BLKT    256

__device__ const float c_class_w[C_CLS] = {
    0.8373f, 0.918f,  0.866f,  1.0345f, 1.0166f, 0.9969f, 0.9754f,
    1.0489f, 0.8786f, 1.0023f, 0.9539f, 0.9843f, 1.1116f, 0.9037f,
    1.0865f, 1.0955f, 1.0865f, 1.1529f, 1.0507f};

// ws layout (floats):
// [4..333] hist pred1 (cnt/sw/swnll, stride 110); [1028..1357] hist pred2
// [2048 + s*16 + k] striped set s (0=nv 1=w1 2=wlp1 3=cle1 4=w2 5=wlp2 6=cle2)

__global__ __launch_bounds__(BLKT) void ohem_pers(
    const float* __restrict__ pred1, const float* __restrict__ pred2,
    const int* __restrict__ target, float* __restrict__ ws)
{
    const int bid = blockIdx.x;
    const int tid = threadIdx.x;

    __shared__ float ry[NELEM];       // [pred][ch][col98], y-lerped, single buf
    __shared__ float wtab[C_CLS];
    __shared__ float sh_red[4][8];

    if (tid < C_CLS) wtab[tid] = c_class_w[tid];

    const float scl = (float)H_IN / (float)H_OUT;

    // ---- fixed per-thread column-run geometry (4-px half-runs) ----
    int col, xs_h, npx;
    if (tid < 194) {
        col = tid >> 1;
        int xs = ((2 * col + 1) * 769 + 96) / 194;
        int xe = min(((2 * col + 3) * 769 + 96) / 194, 769);
        int half = tid & 1;
        xs_h = xs + half * 4;
        npx  = half ? max(xe - xs - 4, 0) : min(xe - xs, 4);
    } else if (tid == 194) {          // left clamp region: x 0..3, fx = 0
        col = 0; xs_h = 0; npx = 4;
    } else {
        col = 0; xs_h = 0; npx = 0;
    }
    const float hstep = (tid == 194) ? 0.0f : scl;
    const float fx0   = (tid == 194) ? 0.0f
                      : fmaf((float)xs_h + 0.5f, scl, -0.5f) - (float)col;

    const int r0 = bid, r1 = bid + GRIDB;

    float a_nv = 0.f;
    float a_w1 = 0.f, a_wlp1 = 0.f, a_cle1 = 0.f;
    float a_w2 = 0.f, a_wlp2 = 0.f, a_cle2 = 0.f;

    float rA[NSLOT], rB[NSLOT];
    int   tgA[4], tgB[4];

    // ================= prologue: stage row r0 =================
    {
        int n = r0 / H_OUT;
        int y = r0 - n * H_OUT;
        float sy = fmaxf(fmaf((float)y + 0.5f, scl, -0.5f), 0.0f);
        int   y0 = min((int)sy, H_IN - 1);
        float fy = sy - (float)y0;
        int   y1 = min(y0 + 1, H_IN - 1);
        const float* bp0 = pred1 + (size_t)n * CHW_IN;
        const float* bp1 = pred2 + (size_t)n * CHW_IN;

        int rowbase = r0 * W_OUT;
        #pragma unroll
        for (int k = 0; k < 4; ++k)
            tgA[k] = target[rowbase + min(xs_h + k, W_OUT - 1)];

        #pragma unroll
        for (int s = 0; s < NSLOT; ++s) {
            int gj  = min(s * BLKT + tid, NELEM - 1);
            int p   = gj / PCR;
            int rem = gj - p * PCR;
            int c   = rem / ROWP;
            int cc  = rem - c * ROWP;
            int gcol = min(cc, W_IN - 1);
            const float* bp = p ? bp1 : bp0;
            int off = c * HW_IN + gcol;
            rA[s] = bp[off + y0 * W_IN];
            rB[s] = bp[off + y1 * W_IN];
        }
        #pragma unroll
        for (int s = 0; s < NSLOT; ++s) {
            int j = s * BLKT + tid;
            if (j < NELEM) ry[j] = fmaf(fy, rB[s] - rA[s], rA[s]);
        }
    }
    __syncthreads();

    // ========== iter 0: issue row-r1 loads, compute row r0 ==========
    float fy1;
    {
        int n = r1 / H_OUT;
        int y = r1 - n * H_OUT;
        float sy = fmaxf(fmaf((float)y + 0.5f, scl, -0.5f), 0.0f);
        int   y0 = min((int)sy, H_IN - 1);
        fy1 = sy - (float)y0;
        int   y1 = min(y0 + 1, H_IN - 1);
        const float* bp0 = pred1 + (size_t)n * CHW_IN;
        const float* bp1 = pred2 + (size_t)n * CHW_IN;

        int rowbase = r1 * W_OUT;
        #pragma unroll
        for (int k = 0; k < 4; ++k)
            tgB[k] = target[rowbase + min(xs_h + k, W_OUT - 1)];

        #pragma unroll
        for (int s = 0; s < NSLOT; ++s) {
            int gj  = min(s * BLKT + tid, NELEM - 1);
            int p   = gj / PCR;
            int rem = gj - p * PCR;
            int c   = rem / ROWP;
            int cc  = rem - c * ROWP;
            int gcol = min(cc, W_IN - 1);
            const float* bp = p ? bp1 : bp0;
            int off = c * HW_IN + gcol;
            rA[s] = bp[off + y0 * W_IN];   // in flight during compute below
            rB[s] = bp[off + y1 * W_IN];
        }
    }

    // ---- compute a row: macro'd as a lambda over (tg, accumulate) ----
    auto compute_row = [&](const int tg[4]) {
        const float* ry1 = ry;
        const float* ry2 = ry + PCR;
        float s1[4] = {0.f, 0.f, 0.f, 0.f};
        float s2[4] = {0.f, 0.f, 0.f, 0.f};
        #pragma unroll
        for (int c = 0; c < C_CLS; ++c) {
            float a1 = ry1[c * ROWP + col], b1 = ry1[c * ROWP + col + 1];
            float a2 = ry2[c * ROWP + col], b2 = ry2[c * ROWP + col + 1];
            float d1 = b1 - a1, d2 = b2 - a2;
            float e1 = __expf(fmaf(fx0, d1, a1));
            float e2 = __expf(fmaf(fx0, d2, a2));
            float g1 = __expf(hstep * d1);
            float g2 = __expf(hstep * d2);
            #pragma unroll
            for (int k = 0; k < 4; ++k) {
                s1[k] += e1; e1 *= g1;
                s2[k] += e2; e2 *= g2;
            }
        }
        #pragma unroll
        for (int k = 0; k < 4; ++k) {
            if (k < npx) {
                int t = tg[k];
                if (t != IGNORE_LBL) {
                    float fxk = fmaf((float)k, hstep, fx0);
                    float u0 = ry1[t * ROWP + col], u1 = ry1[t * ROWP + col + 1];
                    float v0 = ry2[t * ROWP + col], v1 = ry2[t * ROWP + col + 1];
                    float lt1 = fmaf(fxk, u1 - u0, u0);
                    float lt2 = fmaf(fxk, v1 - v0, v0);
                    float w   = wtab[t];
                    float nll1 = __logf(s1[k]) - lt1;
                    float nll2 = __logf(s2[k]) - lt2;
                    a_nv += 1.0f;
                    if (nll1 >= NLL_THR) {
                        a_w1 += w; a_wlp1 = fmaf(w, nll1, a_wlp1); a_cle1 += 1.f;
                    } else {
                        float p = __expf(-nll1);
                        int b = min(max((int)((p - 0.7f) * (109.f / 0.3f)), 0), NHI - 1);
                        atomicAdd(&ws[4 + b],   1.f);
                        atomicAdd(&ws[114 + b], w);
                        atomicAdd(&ws[224 + b], w * nll1);
                    }
                    if (nll2 >= NLL_THR) {
                        a_w2 += w; a_wlp2 = fmaf(w, nll2, a_wlp2); a_cle2 += 1.f;
                    } else {
                        float p = __expf(-nll2);
                        int b = min(max((int)((p - 0.7f) * (109.f / 0.3f)), 0), NHI - 1);
                        atomicAdd(&ws[ACC_STRIDE + 4 + b],   1.f);
                        atomicAdd(&ws[ACC_STRIDE + 114 + b], w);
                        atomicAdd(&ws[ACC_STRIDE + 224 + b], w * nll2);
                    }
                }
            }
        }
    };

    compute_row(tgA);
    __syncthreads();                       // all reads of ry (row r0) done

    // ---- write staged row r1 (compiler waits on the in-flight loads) ----
    #pragma unroll
    for (int s = 0; s < NSLOT; ++s) {
        int j = s * BLKT + tid;
        if (j < NELEM) ry[j] = fmaf(fy1, rB[s] - rA[s], rA[s]);
    }
    __syncthreads();

    // ========== iter 1: compute row r1 ==========
    compute_row(tgB);

    // ---- block reduce (7 values) + striped atomics ----
    #pragma unroll
    for (int off = 32; off > 0; off >>= 1) {
        a_nv   += __shfl_down(a_nv, off);
        a_w1   += __shfl_down(a_w1, off);
        a_wlp1 += __shfl_down(a_wlp1, off);
        a_cle1 += __shfl_down(a_cle1, off);
        a_w2   += __shfl_down(a_w2, off);
        a_wlp2 += __shfl_down(a_wlp2, off);
        a_cle2 += __shfl_down(a_cle2, off);
    }
    int lane = tid & 63;
    int wv   = tid >> 6;
    if (lane == 0) {
        sh_red[wv][0] = a_nv;
        sh_red[wv][1] = a_w1; sh_red[wv][2] = a_wlp1; sh_red[wv][3] = a_cle1;
        sh_red[wv][4] = a_w2; sh_red[wv][5] = a_wlp2; sh_red[wv][6] = a_cle2;
    }
    __syncthreads();
    if (tid == 0) {
        float r[7] = {0, 0, 0, 0, 0, 0, 0};
        #pragma unroll
        for (int i = 0; i < 4; ++i)
            #pragma unroll
            for (int j = 0; j < 7; ++j) r[j] += sh_red[i][j];
        float* acc = ws + SET_BASE + (bid & (NSETS - 1)) * 16;
        #pragma unroll
        for (int j = 0; j < 7; ++j) atomicAdd(&acc[j], r[j]);
    }
}

__global__ void ohem_finalize(const float* __restrict__ ws, float* __restrict__ out)
{
    int lane = threadIdx.x;   // 0..63
    float v[7];
    #pragma unroll
    for (int k = 0; k < 7; ++k) v[k] = ws[SET_BASE + lane * 16 + k];
    #pragma unroll
    for (int off = 32; off > 0; off >>= 1) {
        #pragma unroll
        for (int k = 0; k < 7; ++k) v[k] += __shfl_down(v[k], off);
    }
    if (lane != 0) return;

    float nv = v[0];
    float loss[2];
    for (int pr = 0; pr < 2; ++pr) {
        const float* a = ws + pr * ACC_STRIDE;
        float sw   = pr ? v[4] : v[1];
        float swlp = pr ? v[5] : v[2];
        float cle  = pr ? v[6] : v[3];
        float l;
        if (nv <= (float)MIN_KEPT) {
            float tw = sw, twlp = swlp;
            for (int b = 0; b < NHI; ++b) { tw += a[114 + b]; twlp += a[224 + b]; }
            l = twlp / tw;
        } else if (cle >= (float)MIN_KEPT) {
            l = swlp / sw;
        } else {
            float cum = cle, tw = sw, twlp = swlp;
            for (int b = 0; b < NHI; ++b) {
                cum  += a[4 + b];
                tw   += a[114 + b];
                twlp += a[224 + b];
                if (cum >= (float)MIN_KEPT) break;
            }
            l = twlp / tw;
        }
        loss[pr] = l;
    }
    out[0] = 0.4f * loss[0] + loss[1];
}

extern "C" void kernel_launch(void* const* d_in, const int* in_sizes, int n_in,
                              void* d_out, int out_size, void* d_ws, size_t ws_size,
                              hipStream_t stream)
{
    const float* pred1  = (const float*)d_in[0];
    const float* pred2  = (const float*)d_in[1];
    const int*   target = (const int*)d_in[2];
    float* out = (float*)d_out;
    float* ws  = (float*)d_ws;

    hipMemsetAsync(d_ws, 0, (SET_BASE + NSETS * 16) * sizeof(float), stream);

    ohem_pers<<<dim3(GRIDB), BLKT, 0, stream>>>(pred1, pred2, target, ws);
    ohem_finalize<<<1, 64, 0, stream>>>(ws, out);
}